// Round 7
// baseline (403.519 us; speedup 1.0000x reference)
//
#include <hip/hip_runtime.h>
#include <hip/hip_bf16.h>

// ---------------------------------------------------------------------------
// WindowShiftedMDTA fused kernel, v7 (MI355X / gfx950).
//
// Math fact: with shift = window/2 the reference's shift-mask is all ones =>
// output == unshifted branch only.  fp32 I/O, bf16 MFMA compute (validated:
// absmax 4.9e-4 vs threshold 1.79e-3, rounds 2 and 6).
//
// v6 -> v7 (post-mortem: K16 MFMA ~15cy ~= K32 cycles at half FLOPs; 80% idle
// from phase-serial structure + 8 barriers):
//   * q/k/v GEMMs use 16x16x32 MFMA (C/D tile layout is shape-determined, so
//     the register-chaining into S/PV is unchanged); b128 x-frag reads.
//   * Stage xq-half + xkv-half together; ONE merged loop computes q,k,v with
//     3 independent accumulator streams + depth-1 weight prefetch.
//   * Barriers 8 -> 5.
// S and PV keep K16 chaining (consume 4-elem C/D quads directly).
//
// LDS 64KB -> 2 blocks/CU, 8 waves each.
//   [0,16384):     xq half-stage  [64 pos][128 c] panels (pos*256 + swz)
//   [16384,32768): xkv half-stage (same layout)
//   [0,32768) later: a-exchange [64 pos][256 c] (pos*512 + swz)
//   [32768,65536): per-wave 4KB v tile [32 d][64 m]
//   PI(p) = (p ^ (p>>3)) & 7.
// ---------------------------------------------------------------------------

typedef short bf16x4 __attribute__((ext_vector_type(4)));
typedef short bf16x8 __attribute__((ext_vector_type(8)));
typedef float f32x4  __attribute__((ext_vector_type(4)));
typedef unsigned short ushort_t;

#define MFMA_K16(A_, B_, C_) __builtin_amdgcn_mfma_f32_16x16x16bf16_1k((A_), (B_), (C_), 0, 0, 0)
#define MFMA_K32(A_, B_, C_) __builtin_amdgcn_mfma_f32_16x16x32_bf16((A_), (B_), (C_), 0, 0, 0)

__device__ __forceinline__ short f2b(float f) {
  __hip_bfloat16 h = __float2bfloat16(f);
  return __builtin_bit_cast(short, h);
}
__device__ __forceinline__ bf16x4 cvt4(f32x4 v, float sc) {
  bf16x4 r;
  r[0] = f2b(v[0] * sc); r[1] = f2b(v[1] * sc);
  r[2] = f2b(v[2] * sc); r[3] = f2b(v[3] * sc);
  return r;
}
__device__ __forceinline__ int PI(int p) { return (p ^ (p >> 3)) & 7; }

template<bool B16>
__device__ __forceinline__ bf16x8 ldw8(const void* W, int row, int c0) {
  if constexpr (B16) {
    return *(const bf16x8*)((const ushort_t*)W + (row << 8) + c0);
  } else {
    const float* p = (const float*)W + (row << 8) + c0;
    const float4 x = *(const float4*)p, y = *(const float4*)(p + 4);
    bf16x8 f;
    f[0] = f2b(x.x); f[1] = f2b(x.y); f[2] = f2b(x.z); f[3] = f2b(x.w);
    f[4] = f2b(y.x); f[5] = f2b(y.y); f[6] = f2b(y.z); f[7] = f2b(y.w);
    return f;
  }
}

constexpr int SMEM_BYTES = 65536;

__global__ void wconv(const float* __restrict__ a, const float* __restrict__ b,
                      const float* __restrict__ c, const float* __restrict__ d,
                      ushort_t* __restrict__ o) {
  const int gid = blockIdx.x * 256 + threadIdx.x;        // 65536 float4-quads
  const int which = gid >> 14;
  const int idx = (gid & 16383) * 4;
  const float* src = which == 0 ? a : which == 1 ? b : which == 2 ? c : d;
  const float4 v = *(const float4*)(src + idx);
  bf16x4 w; w[0] = f2b(v.x); w[1] = f2b(v.y); w[2] = f2b(v.z); w[3] = f2b(v.w);
  *(bf16x4*)(o + which * 65536 + idx) = w;
}

// Stage one 128-channel half of one tensor into a 16KB region
// ([64 pos][128 c] swizzled col-major).
__device__ __forceinline__ void stage_half(char* dst, const float* __restrict__ src,
                                           int coff, int tid, size_t ibase, int xoff) {
  #pragma unroll
  for (int j = 0; j < 2; ++j) {
    const int u = j * 512 + tid;                 // 1024 units = 128c x 8 rows
    const int c = u >> 3, hr = u & 7;
    const size_t gg = ibase + (size_t)(c + coff) * 36864 + (size_t)(xoff + hr * 192);
    const float4 a0 = *(const float4*)(src + gg);
    const float4 a1 = *(const float4*)(src + gg + 4);
    const float vv[8] = {a0.x, a0.y, a0.z, a0.w, a1.x, a1.y, a1.z, a1.w};
    #pragma unroll
    for (int w = 0; w < 8; ++w) {
      const int pos = hr * 8 + w;
      const unsigned ad = (unsigned)(pos * 256 + (((c >> 3) ^ PI(pos)) << 4) + (c & 7) * 2);
      *(short*)(dst + ad) = f2b(vv[w]);
    }
  }
}

// x fragment (B-operand, col=pos, k = 8 consecutive channels): one ds_read_b128.
__device__ __forceinline__ bf16x8 xfrag8(const char* base, int kt, int nt, int l15, int g) {
  const int pos = nt * 16 + l15;
  const int c0 = kt * 32 + g * 8;                // 8-aligned
  const unsigned ad = (unsigned)(pos * 256 + (((c0 >> 3) ^ PI(pos)) << 4));
  return *(const bf16x8*)(base + ad);
}

template<bool WB16>
__global__ __launch_bounds__(512, 4) void wsmdta_main(
    const float* __restrict__ xq, const float* __restrict__ xkv,
    const float* __restrict__ temp,
    const void* __restrict__ Wq, const void* __restrict__ Wk,
    const void* __restrict__ Wv, const void* __restrict__ Wo,
    float* __restrict__ out)
{
  extern __shared__ __align__(16) char smem[];
  const int tid = threadIdx.x, lane = tid & 63, wv = tid >> 6;
  const int l15 = lane & 15, g = lane >> 4;

  // XCD-bijective swizzle (1152 = 8 XCD * 144).
  const int bid = blockIdx.x;
  const int wid = (bid & 7) * 144 + (bid >> 3);
  const int b  = wid / 576, rw = wid - b * 576;
  const int wh = rw / 24,   ww = rw - wh * 24;
  const int xoff = wh * 1536 + ww * 8;
  const size_t ibase = (size_t)b * 9437184;

  char* const XQ_ST  = smem;
  char* const XKV_ST = smem + 16384;
  const unsigned VB = 32768u + (unsigned)wv * 4096u;
  const f32x4 fzero = {0.f, 0.f, 0.f, 0.f};
  const int h = wv;                                      // head of this wave
  const float tm = temp[h];

  f32x4 qcd[2][4], kcd[2][4], vcd[2][4];
  #pragma unroll
  for (int dj = 0; dj < 2; ++dj)
    #pragma unroll
    for (int nt = 0; nt < 4; ++nt) {
      qcd[dj][nt] = fzero; kcd[dj][nt] = fzero; vcd[dj][nt] = fzero;
    }

  // ======= merged q/k/v GEMMs over two 128-channel halves ==================
  #pragma unroll
  for (int half = 0; half < 2; ++half) {
    if (half) __syncthreads();                           // B2: h0 reads done
    stage_half(XQ_ST,  xq,  half * 128, tid, ibase, xoff);
    stage_half(XKV_ST, xkv, half * 128, tid, ibase, xoff);
    __syncthreads();                                     // B1/B3: staging visible
    const int cg = half * 128;

    bf16x8 wq0 = ldw8<WB16>(Wq, h * 32 + l15,      cg + g * 8);
    bf16x8 wq1 = ldw8<WB16>(Wq, h * 32 + 16 + l15, cg + g * 8);
    bf16x8 wk0 = ldw8<WB16>(Wk, h * 32 + l15,      cg + g * 8);
    bf16x8 wk1 = ldw8<WB16>(Wk, h * 32 + 16 + l15, cg + g * 8);
    bf16x8 wv0 = ldw8<WB16>(Wv, h * 32 + l15,      cg + g * 8);
    bf16x8 wv1 = ldw8<WB16>(Wv, h * 32 + 16 + l15, cg + g * 8);

    #pragma unroll
    for (int kt = 0; kt < 4; ++kt) {
      bf16x8 nq0, nq1, nk0, nk1, nv0, nv1;
      if (kt < 3) {                                      // depth-1 W prefetch
        const int c1 = cg + (kt + 1) * 32 + g * 8;
        nq0 = ldw8<WB16>(Wq, h * 32 + l15, c1);  nq1 = ldw8<WB16>(Wq, h * 32 + 16 + l15, c1);
        nk0 = ldw8<WB16>(Wk, h * 32 + l15, c1);  nk1 = ldw8<WB16>(Wk, h * 32 + 16 + l15, c1);
        nv0 = ldw8<WB16>(Wv, h * 32 + l15, c1);  nv1 = ldw8<WB16>(Wv, h * 32 + 16 + l15, c1);
      }
      bf16x8 xfq[4], xfk[4];
      #pragma unroll
      for (int nt = 0; nt < 4; ++nt) {
        xfq[nt] = xfrag8(XQ_ST,  kt, nt, l15, g);
        xfk[nt] = xfrag8(XKV_ST, kt, nt, l15, g);
      }
      #pragma unroll
      for (int nt = 0; nt < 4; ++nt) {
        qcd[0][nt] = MFMA_K32(wq0, xfq[nt], qcd[0][nt]); // C[d][pos]
        qcd[1][nt] = MFMA_K32(wq1, xfq[nt], qcd[1][nt]);
        kcd[0][nt] = MFMA_K32(wk0, xfk[nt], kcd[0][nt]); // C[d][m]
        kcd[1][nt] = MFMA_K32(wk1, xfk[nt], kcd[1][nt]);
        vcd[0][nt] = MFMA_K32(wv0, xfk[nt], vcd[0][nt]); // C[d][m]
        vcd[1][nt] = MFMA_K32(wv1, xfk[nt], vcd[1][nt]);
      }
      if (kt < 3) { wq0 = nq0; wq1 = nq1; wk0 = nk0; wk1 = nk1; wv0 = nv0; wv1 = nv1; }
    }
  }

  // qT/kT -> bf16 K16 fragments (k = d = 4g+r matches A/B frag k = g*4+j).
  bf16x4 qb[2][4], kb[2][4];
  #pragma unroll
  for (int dj = 0; dj < 2; ++dj)
    #pragma unroll
    for (int nt = 0; nt < 4; ++nt) {
      qb[dj][nt] = cvt4(qcd[dj][nt], 1.f);
      kb[dj][nt] = cvt4(kcd[dj][nt], 1.f);
    }

  // v -> per-wave LDS tile [32 d][64 m].
  #pragma unroll
  for (int dj = 0; dj < 2; ++dj)
    #pragma unroll
    for (int mt = 0; mt < 4; ++mt) {
      const bf16x4 q = cvt4(vcd[dj][mt], 1.f);
      const int m = mt * 16 + l15;
      #pragma unroll
      for (int r = 0; r < 4; ++r) {
        const int d = dj * 16 + 4 * g + r;
        const unsigned ad = VB + (unsigned)(d * 128 + (((m >> 3) ^ (d & 7)) << 4) + (m & 7) * 2);
        *(short*)(smem + ad) = q[r];
      }
    }

  // ======= S = kT^T.qT in registers (K=16 x 2) =============================
  f32x4 s[4][4];
  #pragma unroll
  for (int mt = 0; mt < 4; ++mt)
    #pragma unroll
    for (int nt = 0; nt < 4; ++nt) {
      s[mt][nt] = MFMA_K16(kb[0][mt], qb[0][nt], fzero); // C[m][n]
      s[mt][nt] = MFMA_K16(kb[1][mt], qb[1][nt], s[mt][nt]);
    }

  // ======= softmax over m; P stays in registers ============================
  bf16x4 Pb[4][4];
  #pragma unroll
  for (int nt = 0; nt < 4; ++nt) {
    float mx = -1e30f;
    #pragma unroll
    for (int mt = 0; mt < 4; ++mt)
      #pragma unroll
      for (int r = 0; r < 4; ++r) {
        const float v = s[mt][nt][r] * tm;
        s[mt][nt][r] = v;
        mx = fmaxf(mx, v);
      }
    mx = fmaxf(mx, __shfl_xor(mx, 16));
    mx = fmaxf(mx, __shfl_xor(mx, 32));
    float sum = 0.f;
    #pragma unroll
    for (int mt = 0; mt < 4; ++mt)
      #pragma unroll
      for (int r = 0; r < 4; ++r) {
        const float p = __expf(s[mt][nt][r] - mx);
        s[mt][nt][r] = p;
        sum += p;
      }
    sum += __shfl_xor(sum, 16);
    sum += __shfl_xor(sum, 32);
    const float ri = 1.f / sum;
    #pragma unroll
    for (int mt = 0; mt < 4; ++mt) Pb[mt][nt] = cvt4(s[mt][nt], ri);
  }

  // ======= PV: aT = v.P (A = v from LDS, B = P regs; K16) ==================
  f32x4 pcd[2][4];
  #pragma unroll
  for (int dj = 0; dj < 2; ++dj)
    #pragma unroll
    for (int nt = 0; nt < 4; ++nt) pcd[dj][nt] = fzero;
  #pragma unroll
  for (int mt = 0; mt < 4; ++mt)
    #pragma unroll
    for (int dj = 0; dj < 2; ++dj) {
      const int d = dj * 16 + l15;
      const unsigned ad = VB + (unsigned)(d * 128 + (((mt * 2 + (g >> 1)) ^ (d & 7)) << 4) + (g & 1) * 8);
      const bf16x4 vf = *(const bf16x4*)(smem + ad);     // (row=d, k=m)
      #pragma unroll
      for (int nt = 0; nt < 4; ++nt)
        pcd[dj][nt] = MFMA_K16(vf, Pb[mt][nt], pcd[dj][nt]);  // C[d][n]
    }

  __syncthreads();   // B4: all staging reads done; [0,32768) becomes a-LDS

  // a (normalized) -> a-LDS [64 pos][256 c], b64 writes.
  #pragma unroll
  for (int dj = 0; dj < 2; ++dj)
    #pragma unroll
    for (int nt = 0; nt < 4; ++nt) {
      const bf16x4 q = cvt4(pcd[dj][nt], 1.f);
      const int pos = nt * 16 + l15;
      const int c0 = h * 32 + dj * 16 + 4 * g;
      const unsigned ad = (unsigned)(pos * 512 + (((c0 >> 3) ^ PI(pos)) << 4) + (c0 & 7) * 2);
      *(bf16x4*)(smem + ad) = q;
    }
  __syncthreads();   // B5: all heads' a ready

  // ======= out^T = a.Wo (K=256, K32 MFMA, b128 a-reads, W prefetch) ========
  f32x4 ocd[4][2];
  #pragma unroll
  for (int nt = 0; nt < 4; ++nt) { ocd[nt][0] = fzero; ocd[nt][1] = fzero; }
  {
    bf16x8 w0 = ldw8<WB16>(Wo, wv * 32 + l15,      g * 8);
    bf16x8 w1 = ldw8<WB16>(Wo, wv * 32 + 16 + l15, g * 8);
    #pragma unroll
    for (int ks = 0; ks < 8; ++ks) {
      bf16x8 n0, n1;
      if (ks < 7) {
        n0 = ldw8<WB16>(Wo, wv * 32 + l15,      (ks + 1) * 32 + g * 8);
        n1 = ldw8<WB16>(Wo, wv * 32 + 16 + l15, (ks + 1) * 32 + g * 8);
      }
      #pragma unroll
      for (int nt = 0; nt < 4; ++nt) {
        const int pos = nt * 16 + l15;
        const unsigned ad = (unsigned)(pos * 512 + (((ks * 4 + g) ^ PI(pos)) << 4));
        const bf16x8 af = *(const bf16x8*)(smem + ad);   // A: (row=pos, k=c)
        ocd[nt][0] = MFMA_K32(af, w0, ocd[nt][0]);       // C[pos][c_out]
        ocd[nt][1] = MFMA_K32(af, w1, ocd[nt][1]);
      }
      if (ks < 7) { w0 = n0; w1 = n1; }
    }
  }

  // C/D: col = c_out (fixed/lane), rows = 4 consecutive pos -> float4 stores.
  #pragma unroll
  for (int nt = 0; nt < 4; ++nt)
    #pragma unroll
    for (int ct = 0; ct < 2; ++ct) {
      const int c_out = wv * 32 + ct * 16 + l15;
      const int h_out = nt * 2 + (g >> 1);
      const int w0 = 4 * (g & 1);
      float4 v;
      v.x = ocd[nt][ct][0]; v.y = ocd[nt][ct][1];
      v.z = ocd[nt][ct][2]; v.w = ocd[nt][ct][3];
      *(float4*)(out + ibase + (size_t)c_out * 36864 + (size_t)(xoff + h_out * 192 + w0)) = v;
    }
}

extern "C" void kernel_launch(void* const* d_in, const int* in_sizes, int n_in,
                              void* d_out, int out_size, void* d_ws, size_t ws_size,
                              hipStream_t stream) {
  (void)in_sizes; (void)n_in; (void)out_size;
  const float* xq   = (const float*)d_in[0];
  const float* xkv  = (const float*)d_in[1];
  const float* temp = (const float*)d_in[2];
  const float* Wq   = (const float*)d_in[3];
  const float* Wk   = (const float*)d_in[4];
  const float* Wv   = (const float*)d_in[5];
  const float* Wo   = (const float*)d_in[6];
  float* out = (float*)d_out;

  const bool wb16 = (ws_size >= 4u * 65536u * sizeof(ushort_t));
  if (wb16) {
    ushort_t* wsb = (ushort_t*)d_ws;
    wconv<<<dim3(256), dim3(256), 0, stream>>>(Wq, Wk, Wv, Wo, wsb);
    (void)hipFuncSetAttribute((const void*)&wsmdta_main<true>,
                              hipFuncAttributeMaxDynamicSharedMemorySize, SMEM_BYTES);
    wsmdta_main<true><<<dim3(1152), dim3(512), SMEM_BYTES, stream>>>(
        xq, xkv, temp, wsb, wsb + 65536, wsb + 131072, wsb + 196608, out);
  } else {
    (void)hipFuncSetAttribute((const void*)&wsmdta_main<false>,
                              hipFuncAttributeMaxDynamicSharedMemorySize, SMEM_BYTES);
    wsmdta_main<false><<<dim3(1152), dim3(512), SMEM_BYTES, stream>>>(
        xq, xkv, temp, Wq, Wk, Wv, Wo, out);
  }
}

// Round 9
// 255.416 us; speedup vs baseline: 1.5799x; 1.5799x over previous
//
#include <hip/hip_runtime.h>
#include <hip/hip_bf16.h>

// ---------------------------------------------------------------------------
// WindowShiftedMDTA fused, v9 (MI355X / gfx950).
//
// Math fact: with shift = window/2 the reference's shift-mask is all ones =>
// output == unshifted branch only.  fp32 I/O, bf16 MFMA compute (validated
// rounds 2/6/7: absmax 4.9e-4 vs threshold 1.79e-3).
//
// v8 -> v9: ONE bug fix.  k2's A-tile staging staged 768 of the 1536 16B
// chunks (j<3 instead of j<6) -> t in [48,96) read uninitialized LDS -> NaN.
// Structure unchanged:
//   k1: per (window, head-group-of-4): q/k/v GEMMs (K32), S+softmax+PV (K16
//       register chaining), a -> workspace dense [win][pos 64][c 256] bf16.
//       32KB LDS -> 4 blocks/CU (desynchronized barriers).
//   k2: out = Wo . A; stores are 64B runs along W (kills the 4.2x write
//       amplification measured in v6).
// Fallback (ws too small): validated v6 single-kernel path.
// ---------------------------------------------------------------------------

typedef short bf16x4 __attribute__((ext_vector_type(4)));
typedef short bf16x8 __attribute__((ext_vector_type(8)));
typedef float f32x4  __attribute__((ext_vector_type(4)));
typedef unsigned short ushort_t;

#define MFMA_K16(A_, B_, C_) __builtin_amdgcn_mfma_f32_16x16x16bf16_1k((A_), (B_), (C_), 0, 0, 0)
#define MFMA_K32(A_, B_, C_) __builtin_amdgcn_mfma_f32_16x16x32_bf16((A_), (B_), (C_), 0, 0, 0)

__device__ __forceinline__ short f2b(float f) {
  __hip_bfloat16 h = __float2bfloat16(f);
  return __builtin_bit_cast(short, h);
}
__device__ __forceinline__ bf16x4 cvt4(f32x4 v, float sc) {
  bf16x4 r;
  r[0] = f2b(v[0] * sc); r[1] = f2b(v[1] * sc);
  r[2] = f2b(v[2] * sc); r[3] = f2b(v[3] * sc);
  return r;
}
__device__ __forceinline__ int PI(int p) { return (p ^ (p >> 3)) & 7; }

template<bool B16>
__device__ __forceinline__ bf16x8 ldw8(const void* W, int row, int c0) {
  if constexpr (B16) {
    return *(const bf16x8*)((const ushort_t*)W + (row << 8) + c0);
  } else {
    const float* p = (const float*)W + (row << 8) + c0;
    const float4 x = *(const float4*)p, y = *(const float4*)(p + 4);
    bf16x8 f;
    f[0] = f2b(x.x); f[1] = f2b(x.y); f[2] = f2b(x.z); f[3] = f2b(x.w);
    f[4] = f2b(y.x); f[5] = f2b(y.y); f[6] = f2b(y.z); f[7] = f2b(y.w);
    return f;
  }
}
__device__ __forceinline__ bf16x8 ldw8b(const ushort_t* W, int row, int c0) {
  return *(const bf16x8*)(W + (row << 8) + c0);
}

// Stage one 128-channel half of one tensor: [64 pos][128 c] swizzled panels
// (validated in v6/v7).  NT = threads in block.
template<int NT>
__device__ __forceinline__ void stage_half(char* dst, const float* __restrict__ src,
                                           int coff, int tid, size_t ibase, int xoff) {
  #pragma unroll
  for (int j = 0; j < 1024 / NT; ++j) {
    const int u = j * NT + tid;                  // 1024 units = 128c x 8 rows
    const int c = u >> 3, hr = u & 7;
    const size_t gg = ibase + (size_t)(c + coff) * 36864 + (size_t)(xoff + hr * 192);
    const float4 a0 = *(const float4*)(src + gg);
    const float4 a1 = *(const float4*)(src + gg + 4);
    const float vv[8] = {a0.x, a0.y, a0.z, a0.w, a1.x, a1.y, a1.z, a1.w};
    #pragma unroll
    for (int w = 0; w < 8; ++w) {
      const int pos = hr * 8 + w;
      const unsigned ad = (unsigned)(pos * 256 + (((c >> 3) ^ PI(pos)) << 4) + (c & 7) * 2);
      *(short*)(dst + ad) = f2b(vv[w]);
    }
  }
}

// x fragment (B-operand, col=pos, k = 8 consecutive channels): ds_read_b128.
__device__ __forceinline__ bf16x8 xfrag8(const char* base, int kt, int nt, int l15, int g) {
  const int pos = nt * 16 + l15;
  const int c0 = kt * 32 + g * 8;
  const unsigned ad = (unsigned)(pos * 256 + (((c0 >> 3) ^ PI(pos)) << 4));
  return *(const bf16x8*)(base + ad);
}

__global__ void wconv(const float* __restrict__ a, const float* __restrict__ b,
                      const float* __restrict__ c, const float* __restrict__ d,
                      ushort_t* __restrict__ o) {
  const int gid = blockIdx.x * 256 + threadIdx.x;
  const int which = gid >> 14;
  const int idx = (gid & 16383) * 4;
  const float* src = which == 0 ? a : which == 1 ? b : which == 2 ? c : d;
  const float4 v = *(const float4*)(src + idx);
  bf16x4 w; w[0] = f2b(v.x); w[1] = f2b(v.y); w[2] = f2b(v.z); w[3] = f2b(v.w);
  *(bf16x4*)(o + which * 65536 + idx) = w;
}

// ======================= k1: q/k/v + attention -> a ========================
// 2304 blocks = 1152 windows x 2 head-groups; 256 threads = 4 waves, 1 head
// per wave.  LDS 32KB: [0,16K) stage; [16K,32K) 4x4KB per-wave v/a tiles.
__global__ __launch_bounds__(256, 4) void k1_attn(
    const float* __restrict__ xq, const float* __restrict__ xkv,
    const float* __restrict__ temp,
    const ushort_t* __restrict__ Wq, const ushort_t* __restrict__ Wk,
    const ushort_t* __restrict__ Wv, ushort_t* __restrict__ abuf)
{
  __shared__ __align__(16) char smem[32768];
  const int tid = threadIdx.x, lane = tid & 63, wv4 = tid >> 6;
  const int l15 = lane & 15, g = lane >> 4;

  const int bid = blockIdx.x;                    // 2304 = 8 XCD * 288
  const int wid = (bid & 7) * 288 + (bid >> 3);
  const int win = wid >> 1, hg = wid & 1;
  const int b  = win / 576, rw = win - b * 576;
  const int wh = rw / 24,   ww = rw - wh * 24;
  const int xoff = wh * 1536 + ww * 8;
  const size_t ibase = (size_t)b * 9437184;

  char* const ST = smem;
  const unsigned PW = 16384u + (unsigned)wv4 * 4096u;  // v tile, then a tile
  const f32x4 fzero = {0.f, 0.f, 0.f, 0.f};
  const int h = hg * 4 + wv4;
  const float tm = temp[h];

  // ---- q GEMM over two halves (K32) ----------------------------------
  f32x4 qcd[2][4];
  #pragma unroll
  for (int dj = 0; dj < 2; ++dj)
    #pragma unroll
    for (int nt = 0; nt < 4; ++nt) qcd[dj][nt] = fzero;

  #pragma unroll
  for (int half = 0; half < 2; ++half) {
    if (half) __syncthreads();
    stage_half<256>(ST, xq, half * 128, tid, ibase, xoff);
    __syncthreads();
    const int cg = half * 128;
    #pragma unroll
    for (int kt = 0; kt < 4; ++kt) {
      const bf16x8 w0 = ldw8b(Wq, h * 32 + l15,      cg + kt * 32 + g * 8);
      const bf16x8 w1 = ldw8b(Wq, h * 32 + 16 + l15, cg + kt * 32 + g * 8);
      #pragma unroll
      for (int nt = 0; nt < 4; ++nt) {
        const bf16x8 xf = xfrag8(ST, kt, nt, l15, g);
        qcd[0][nt] = MFMA_K32(w0, xf, qcd[0][nt]);  // C: col=pos, rows=d
        qcd[1][nt] = MFMA_K32(w1, xf, qcd[1][nt]);
      }
    }
    __syncthreads();
  }
  bf16x4 qb[2][4];
  #pragma unroll
  for (int dj = 0; dj < 2; ++dj)
    #pragma unroll
    for (int nt = 0; nt < 4; ++nt) qb[dj][nt] = cvt4(qcd[dj][nt], 1.f);

  // ---- k + v GEMMs over two halves (K32) -----------------------------
  f32x4 kcd[2][4], vcd[2][4];
  #pragma unroll
  for (int dj = 0; dj < 2; ++dj)
    #pragma unroll
    for (int nt = 0; nt < 4; ++nt) { kcd[dj][nt] = fzero; vcd[dj][nt] = fzero; }

  #pragma unroll
  for (int half = 0; half < 2; ++half) {
    stage_half<256>(ST, xkv, half * 128, tid, ibase, xoff);
    __syncthreads();
    const int cg = half * 128;
    #pragma unroll
    for (int kt = 0; kt < 4; ++kt) {
      const bf16x8 wk0 = ldw8b(Wk, h * 32 + l15,      cg + kt * 32 + g * 8);
      const bf16x8 wk1 = ldw8b(Wk, h * 32 + 16 + l15, cg + kt * 32 + g * 8);
      const bf16x8 wv0 = ldw8b(Wv, h * 32 + l15,      cg + kt * 32 + g * 8);
      const bf16x8 wv1 = ldw8b(Wv, h * 32 + 16 + l15, cg + kt * 32 + g * 8);
      #pragma unroll
      for (int np = 0; np < 2; ++np) {           // nt pairs: cap live x-frags
        const bf16x8 xf0 = xfrag8(ST, kt, np * 2,     l15, g);
        const bf16x8 xf1 = xfrag8(ST, kt, np * 2 + 1, l15, g);
        kcd[0][np*2]   = MFMA_K32(wk0, xf0, kcd[0][np*2]);
        kcd[1][np*2]   = MFMA_K32(wk1, xf0, kcd[1][np*2]);
        vcd[0][np*2]   = MFMA_K32(wv0, xf0, vcd[0][np*2]);
        vcd[1][np*2]   = MFMA_K32(wv1, xf0, vcd[1][np*2]);
        kcd[0][np*2+1] = MFMA_K32(wk0, xf1, kcd[0][np*2+1]);
        kcd[1][np*2+1] = MFMA_K32(wk1, xf1, kcd[1][np*2+1]);
        vcd[0][np*2+1] = MFMA_K32(wv0, xf1, vcd[0][np*2+1]);
        vcd[1][np*2+1] = MFMA_K32(wv1, xf1, vcd[1][np*2+1]);
      }
    }
    if (half == 0) __syncthreads();
  }

  bf16x4 kb[2][4];
  #pragma unroll
  for (int dj = 0; dj < 2; ++dj)
    #pragma unroll
    for (int mt = 0; mt < 4; ++mt) kb[dj][mt] = cvt4(kcd[dj][mt], 1.f);

  // v -> per-wave LDS tile [32 d][64 m] (wave-private; compiler orders DS).
  #pragma unroll
  for (int dj = 0; dj < 2; ++dj)
    #pragma unroll
    for (int mt = 0; mt < 4; ++mt) {
      const bf16x4 q = cvt4(vcd[dj][mt], 1.f);
      const int m = mt * 16 + l15;
      #pragma unroll
      for (int r = 0; r < 4; ++r) {
        const int d = dj * 16 + 4 * g + r;
        const unsigned ad = PW + (unsigned)(d * 128 + (((m >> 3) ^ (d & 7)) << 4) + (m & 7) * 2);
        *(short*)(smem + ad) = q[r];
      }
    }

  // ---- S = kT^T.qT (K16 register chaining, validated) ----------------
  f32x4 s[4][4];
  #pragma unroll
  for (int mt = 0; mt < 4; ++mt)
    #pragma unroll
    for (int nt = 0; nt < 4; ++nt) {
      s[mt][nt] = MFMA_K16(kb[0][mt], qb[0][nt], fzero);  // C[m][n]
      s[mt][nt] = MFMA_K16(kb[1][mt], qb[1][nt], s[mt][nt]);
    }

  // ---- softmax over m --------------------------------------------------
  bf16x4 Pb[4][4];
  #pragma unroll
  for (int nt = 0; nt < 4; ++nt) {
    float mx = -1e30f;
    #pragma unroll
    for (int mt = 0; mt < 4; ++mt)
      #pragma unroll
      for (int r = 0; r < 4; ++r) {
        const float v = s[mt][nt][r] * tm;
        s[mt][nt][r] = v;
        mx = fmaxf(mx, v);
      }
    mx = fmaxf(mx, __shfl_xor(mx, 16));
    mx = fmaxf(mx, __shfl_xor(mx, 32));
    float sum = 0.f;
    #pragma unroll
    for (int mt = 0; mt < 4; ++mt)
      #pragma unroll
      for (int r = 0; r < 4; ++r) {
        const float p = __expf(s[mt][nt][r] - mx);
        s[mt][nt][r] = p;
        sum += p;
      }
    sum += __shfl_xor(sum, 16);
    sum += __shfl_xor(sum, 32);
    const float ri = 1.f / sum;
    #pragma unroll
    for (int mt = 0; mt < 4; ++mt) Pb[mt][nt] = cvt4(s[mt][nt], ri);
  }

  // ---- PV (K16): A = v from LDS, B = P regs ---------------------------
  f32x4 pcd[2][4];
  #pragma unroll
  for (int dj = 0; dj < 2; ++dj)
    #pragma unroll
    for (int nt = 0; nt < 4; ++nt) pcd[dj][nt] = fzero;
  #pragma unroll
  for (int mt = 0; mt < 4; ++mt)
    #pragma unroll
    for (int dj = 0; dj < 2; ++dj) {
      const int d = dj * 16 + l15;
      const unsigned ad = PW + (unsigned)(d * 128 + (((mt * 2 + (g >> 1)) ^ (d & 7)) << 4) + (g & 1) * 8);
      const bf16x4 vf = *(const bf16x4*)(smem + ad);
      #pragma unroll
      for (int nt = 0; nt < 4; ++nt)
        pcd[dj][nt] = MFMA_K16(vf, Pb[mt][nt], pcd[dj][nt]);  // C[d][n]
    }

  // ---- a -> per-wave LDS tile [64 pos][8 slots x 8B], then global -----
  #pragma unroll
  for (int dj = 0; dj < 2; ++dj)
    #pragma unroll
    for (int nt = 0; nt < 4; ++nt) {
      const bf16x4 q = cvt4(pcd[dj][nt], 1.f);
      const int pos = nt * 16 + l15;
      const int sl = (dj * 4 + g) ^ (pos & 7);
      *(bf16x4*)(smem + PW + (unsigned)(pos * 64 + sl * 8)) = q;
    }
  // read back + store: a[win][pos][c] bf16, 64B runs per pos.
  {
    ushort_t* aw = abuf + (size_t)win * 16384 + h * 32;
    #pragma unroll
    for (int i = 0; i < 8; ++i) {
      const int cid = i * 64 + lane;
      const int pos = cid >> 3, sl = cid & 7;
      const bf16x4 q = *(const bf16x4*)(smem + PW + (unsigned)(pos * 64 + sl * 8));
      const int c0 = ((sl ^ (pos & 7)) << 2);
      *(bf16x4*)(aw + pos * 256 + c0) = q;
    }
  }
}

// ======================= k2: out = Wo . A (image layout) ===================
// 1536 blocks = 2b x 192h x 2 w-halves x 2 co-tiles; 256 threads = 4 waves.
// Wave: 32 co x 96 imgw.  LDS 24KB A-tile [96 t][128 c] swizzled.
__global__ __launch_bounds__(256, 4) void k2_out(
    const ushort_t* __restrict__ Wo, const ushort_t* __restrict__ abuf,
    float* __restrict__ out)
{
  __shared__ __align__(16) char smem[24576];
  const int tid = threadIdx.x, lane = tid & 63, wv4 = tid >> 6;
  const int l15 = lane & 15, g = lane >> 4;

  const int bid = blockIdx.x;                    // 1536 = 8 XCD * 192
  const int wid = (bid & 7) * 192 + (bid >> 3);
  const int ct = wid & 1;
  int r = wid >> 1;
  const int whalf = r & 1; r >>= 1;
  const int h = r % 192, b = r / 192;
  const int wh = h >> 3, ph = h & 7, wstart = whalf * 96;
  const int winbase = b * 576 + wh * 24 + (wstart >> 3);

  f32x4 acc[6][2];
  #pragma unroll
  for (int nt = 0; nt < 6; ++nt) { acc[nt][0] = {0,0,0,0}; acc[nt][1] = {0,0,0,0}; }

  const int corow0 = ct * 128 + wv4 * 32 + l15;

  #pragma unroll
  for (int ki = 0; ki < 2; ++ki) {
    const int kb = ki * 128;
    if (ki) __syncthreads();
    // stage A-tile: 1536 x 16B chunks (6/thread, FIXED from 3/thread).
    #pragma unroll
    for (int j = 0; j < 6; ++j) {
      const int u = j * 256 + tid;
      const int t = u >> 4, ch = u & 15;
      const int win = winbase + (t >> 3);
      const int wpos = ph * 8 + (t & 7);
      const bf16x8 v = *(const bf16x8*)(abuf + (size_t)win * 16384 + wpos * 256 + kb + ch * 8);
      const int sl = ch ^ (t & 7);               // XOR low-3 bits, bijective
      *(bf16x8*)(smem + (unsigned)(t * 256 + sl * 16)) = v;
    }
    __syncthreads();
    #pragma unroll
    for (int sk = 0; sk < 4; ++sk) {
      const int c0 = kb + sk * 32 + g * 8;
      const bf16x8 w0 = ldw8b(Wo, corow0,      c0);
      const bf16x8 w1 = ldw8b(Wo, corow0 + 16, c0);
      #pragma unroll
      for (int nt = 0; nt < 6; ++nt) {
        const int t = nt * 16 + l15;
        const int lch = sk * 4 + g;
        const bf16x8 af = *(const bf16x8*)(smem + (unsigned)(t * 256 + ((lch ^ (t & 7)) << 4)));
        acc[nt][0] = MFMA_K32(w0, af, acc[nt][0]);  // C: col=t, rows=co
        acc[nt][1] = MFMA_K32(w1, af, acc[nt][1]);
      }
    }
  }

  // stores: 64B runs along W.
  #pragma unroll
  for (int nt = 0; nt < 6; ++nt)
    #pragma unroll
    for (int cj = 0; cj < 2; ++cj) {
      const int t = nt * 16 + l15;
      #pragma unroll
      for (int rr = 0; rr < 4; ++rr) {
        const int co = ct * 128 + wv4 * 32 + cj * 16 + 4 * g + rr;
        out[(size_t)b * 9437184 + (size_t)co * 36864 + h * 192 + wstart + t] = acc[nt][cj][rr];
      }
    }
}

// ================= v6 fallback (validated, 276us) ==========================
constexpr int SMEM_OLD = 65536;

template<bool WB16>
__global__ __launch_bounds__(512, 4) void wsmdta_old(
    const float* __restrict__ xq, const float* __restrict__ xkv,
    const float* __restrict__ temp,
    const void* __restrict__ Wq, const void* __restrict__ Wk,
    const void* __restrict__ Wv, const void* __restrict__ Wo,
    float* __restrict__ out)
{
  extern __shared__ __align__(16) char smem[];
  const int tid = threadIdx.x, lane = tid & 63, wv = tid >> 6;
  const int l15 = lane & 15, g = lane >> 4;
  const int bid = blockIdx.x;
  const int wid = (bid & 7) * 144 + (bid >> 3);
  const int b  = wid / 576, rw = wid - b * 576;
  const int wh = rw / 24,   ww = rw - wh * 24;
  const int xoff = wh * 1536 + ww * 8;
  const size_t ibase = (size_t)b * 9437184;
  const unsigned VB = 32768u + (unsigned)wv * 4096u;
  const f32x4 fzero = {0.f, 0.f, 0.f, 0.f};
  const int h = wv;
  const float tm = temp[h];

  f32x4 qcd[2][4];
  #pragma unroll
  for (int dj = 0; dj < 2; ++dj)
    #pragma unroll
    for (int nt = 0; nt < 4; ++nt) qcd[dj][nt] = fzero;
  #pragma unroll
  for (int half = 0; half < 2; ++half) {
    if (half) __syncthreads();
    stage_half<512>(smem, xq, half * 128, tid, ibase, xoff);
    __syncthreads();
    const int cg = half * 128;
    #pragma unroll
    for (int kt = 0; kt < 4; ++kt) {
      const bf16x8 w0 = ldw8<WB16>(Wq, h * 32 + l15,      cg + kt * 32 + g * 8);
      const bf16x8 w1 = ldw8<WB16>(Wq, h * 32 + 16 + l15, cg + kt * 32 + g * 8);
      #pragma unroll
      for (int nt = 0; nt < 4; ++nt) {
        const bf16x8 xf = xfrag8(smem, kt, nt, l15, g);
        qcd[0][nt] = MFMA_K32(w0, xf, qcd[0][nt]);
        qcd[1][nt] = MFMA_K32(w1, xf, qcd[1][nt]);
      }
    }
    __syncthreads();
  }
  bf16x4 qb[2][4];
  #pragma unroll
  for (int dj = 0; dj < 2; ++dj)
    #pragma unroll
    for (int nt = 0; nt < 4; ++nt) qb[dj][nt] = cvt4(qcd[dj][nt], 1.f);

  f32x4 kcd[2][4], vcd[2][4];
  #pragma unroll
  for (int dj = 0; dj < 2; ++dj)
    #pragma unroll
    for (int nt = 0; nt < 4; ++nt) { kcd[dj][nt] = fzero; vcd[dj][nt] = fzero; }
  #pragma unroll
  for (int half = 0; half < 2; ++half) {
    stage_half<512>(smem, xkv, half * 128, tid, ibase, xoff);
    __syncthreads();
    const int cg = half * 128;
    #pragma unroll
    for (int kt = 0; kt < 4; ++kt) {
      const bf16x8 wk0 = ldw8<WB16>(Wk, h * 32 + l15,      cg + kt * 32 + g * 8);
      const bf16x8 wk1 = ldw8<WB16>(Wk, h * 32 + 16 + l15, cg + kt * 32 + g * 8);
      const bf16x8 wv0 = ldw8<WB16>(Wv, h * 32 + l15,      cg + kt * 32 + g * 8);
      const bf16x8 wv1 = ldw8<WB16>(Wv, h * 32 + 16 + l15, cg + kt * 32 + g * 8);
      #pragma unroll
      for (int np = 0; np < 2; ++np) {
        const bf16x8 xf0 = xfrag8(smem, kt, np * 2,     l15, g);
        const bf16x8 xf1 = xfrag8(smem, kt, np * 2 + 1, l15, g);
        kcd[0][np*2]   = MFMA_K32(wk0, xf0, kcd[0][np*2]);
        kcd[1][np*2]   = MFMA_K32(wk1, xf0, kcd[1][np*2]);
        vcd[0][np*2]   = MFMA_K32(wv0, xf0, vcd[0][np*2]);
        vcd[1][np*2]   = MFMA_K32(wv1, xf0, vcd[1][np*2]);
        kcd[0][np*2+1] = MFMA_K32(wk0, xf1, kcd[0][np*2+1]);
        kcd[1][np*2+1] = MFMA_K32(wk1, xf1, kcd[1][np*2+1]);
        vcd[0][np*2+1] = MFMA_K32(wv0, xf1, vcd[0][np*2+1]);
        vcd[1][np*2+1] = MFMA_K32(wv1, xf1, vcd[1][np*2+1]);
      }
    }
    if (half == 0) __syncthreads();
  }
  bf16x4 kb[2][4];
  #pragma unroll
  for (int dj = 0; dj < 2; ++dj)
    #pragma unroll
    for (int mt = 0; mt < 4; ++mt) kb[dj][mt] = cvt4(kcd[dj][mt], 1.f);
  #pragma unroll
  for (int dj = 0; dj < 2; ++dj)
    #pragma unroll
    for (int mt = 0; mt < 4; ++mt) {
      const bf16x4 q = cvt4(vcd[dj][mt], 1.f);
      const int m = mt * 16 + l15;
      #pragma unroll
      for (int rr = 0; rr < 4; ++rr) {
        const int d = dj * 16 + 4 * g + rr;
        const unsigned ad = VB + (unsigned)(d * 128 + (((m >> 3) ^ (d & 7)) << 4) + (m & 7) * 2);
        *(short*)(smem + ad) = q[rr];
      }
    }
  f32x4 s[4][4];
  #pragma unroll
  for (int mt = 0; mt < 4; ++mt)
    #pragma unroll
    for (int nt = 0; nt < 4; ++nt) {
      s[mt][nt] = MFMA_K16(kb[0][mt], qb[0][nt], fzero);
      s[mt][nt] = MFMA_K16(kb[1][mt], qb[1][nt], s[mt][nt]);
    }
  bf16x4 Pb[4][4];
  #pragma unroll
  for (int nt = 0; nt < 4; ++nt) {
    float mx = -1e30f;
    #pragma unroll
    for (int mt = 0; mt < 4; ++mt)
      #pragma unroll
      for (int rr = 0; rr < 4; ++rr) {
        const float v = s[mt][nt][rr] * tm;
        s[mt][nt][rr] = v;
        mx = fmaxf(mx, v);
      }
    mx = fmaxf(mx, __shfl_xor(mx, 16));
    mx = fmaxf(mx, __shfl_xor(mx, 32));
    float sum = 0.f;
    #pragma unroll
    for (int mt = 0; mt < 4; ++mt)
      #pragma unroll
      for (int rr = 0; rr < 4; ++rr) {
        const float p = __expf(s[mt][nt][rr] - mx);
        s[mt][nt][rr] = p;
        sum += p;
      }
    sum += __shfl_xor(sum, 16);
    sum += __shfl_xor(sum, 32);
    const float ri = 1.f / sum;
    #pragma unroll
    for (int mt = 0; mt < 4; ++mt) Pb[mt][nt] = cvt4(s[mt][nt], ri);
  }
  f32x4 pcd[2][4];
  #pragma unroll
  for (int dj = 0; dj < 2; ++dj)
    #pragma unroll
    for (int nt = 0; nt < 4; ++nt) pcd[dj][nt] = fzero;
  #pragma unroll
  for (int mt = 0; mt < 4; ++mt)
    #pragma unroll
    for (int dj = 0; dj < 2; ++dj) {
      const int d = dj * 16 + l15;
      const unsigned ad = VB + (unsigned)(d * 128 + (((mt * 2 + (g >> 1)) ^ (d & 7)) << 4) + (g & 1) * 8);
      const bf16x4 vf = *(const bf16x4*)(smem + ad);
      #pragma unroll
      for (int nt = 0; nt < 4; ++nt)
        pcd[dj][nt] = MFMA_K16(vf, Pb[mt][nt], pcd[dj][nt]);
    }
  __syncthreads();
  #pragma unroll
  for (int dj = 0; dj < 2; ++dj)
    #pragma unroll
    for (int nt = 0; nt < 4; ++nt) {
      const bf16x4 q = cvt4(pcd[dj][nt], 1.f);
      const int pos = nt * 16 + l15;
      const int c0 = h * 32 + dj * 16 + 4 * g;
      const unsigned ad = (unsigned)(pos * 512 + (((c0 >> 3) ^ PI(pos)) << 4) + (c0 & 7) * 2);
      *(bf16x4*)(smem + ad) = q;
    }
  __syncthreads();
  f32x4 ocd[4][2];
  #pragma unroll
  for (int nt = 0; nt < 4; ++nt) { ocd[nt][0] = fzero; ocd[nt][1] = fzero; }
  {
    bf16x8 w0 = ldw8<WB16>(Wo, wv * 32 + l15,      g * 8);
    bf16x8 w1 = ldw8<WB16>(Wo, wv * 32 + 16 + l15, g * 8);
    #pragma unroll
    for (int ks = 0; ks < 8; ++ks) {
      bf16x8 n0, n1;
      if (ks < 7) {
        n0 = ldw8<WB16>(Wo, wv * 32 + l15,      (ks + 1) * 32 + g * 8);
        n1 = ldw8<WB16>(Wo, wv * 32 + 16 + l15, (ks + 1) * 32 + g * 8);
      }
      #pragma unroll
      for (int nt = 0; nt < 4; ++nt) {
        const int pos = nt * 16 + l15;
        const unsigned ad = (unsigned)(pos * 512 + (((ks * 4 + g) ^ PI(pos)) << 4));
        const bf16x8 af = *(const bf16x8*)(smem + ad);
        ocd[nt][0] = MFMA_K32(af, w0, ocd[nt][0]);
        ocd[nt][1] = MFMA_K32(af, w1, ocd[nt][1]);
      }
      if (ks < 7) { w0 = n0; w1 = n1; }
    }
  }
  #pragma unroll
  for (int nt = 0; nt < 4; ++nt)
    #pragma unroll
    for (int ctj = 0; ctj < 2; ++ctj) {
      const int c_out = wv * 32 + ctj * 16 + l15;
      const int h_out = nt * 2 + (g >> 1);
      const int w0o = 4 * (g & 1);
      float4 v;
      v.x = ocd[nt][ctj][0]; v.y = ocd[nt][ctj][1];
      v.z = ocd[nt][ctj][2]; v.w = ocd[nt][ctj][3];
      *(float4*)(out + ibase + (size_t)c_out * 36864 + (size_t)(xoff + h_out * 192 + w0o)) = v;
    }
}

extern "C" void kernel_launch(void* const* d_in, const int* in_sizes, int n_in,
                              void* d_out, int out_size, void* d_ws, size_t ws_size,
                              hipStream_t stream) {
  (void)in_sizes; (void)n_in; (void)out_size;
  const float* xq   = (const float*)d_in[0];
  const float* xkv  = (const float*)d_in[1];
  const float* temp = (const float*)d_in[2];
  const float* Wq   = (const float*)d_in[3];
  const float* Wk   = (const float*)d_in[4];
  const float* Wv   = (const float*)d_in[5];
  const float* Wo   = (const float*)d_in[6];
  float* out = (float*)d_out;

  const size_t W_BYTES = 4u * 65536u * sizeof(ushort_t);          // 512KB
  const size_t A_BYTES = (size_t)1152 * 16384 * sizeof(ushort_t); // 37.75MB

  if (ws_size >= W_BYTES + A_BYTES) {
    ushort_t* wsb  = (ushort_t*)d_ws;
    ushort_t* abuf = wsb + 4 * 65536;
    wconv<<<dim3(256), dim3(256), 0, stream>>>(Wq, Wk, Wv, Wo, wsb);
    k1_attn<<<dim3(2304), dim3(256), 0, stream>>>(
        xq, xkv, temp, wsb, wsb + 65536, wsb + 131072, abuf);
    k2_out<<<dim3(1536), dim3(256), 0, stream>>>(wsb + 196608, abuf, out);
  } else if (ws_size >= W_BYTES) {
    ushort_t* wsb = (ushort_t*)d_ws;
    wconv<<<dim3(256), dim3(256), 0, stream>>>(Wq, Wk, Wv, Wo, wsb);
    (void)hipFuncSetAttribute((const void*)&wsmdta_old<true>,
                              hipFuncAttributeMaxDynamicSharedMemorySize, SMEM_OLD);
    wsmdta_old<true><<<dim3(1152), dim3(512), SMEM_OLD, stream>>>(
        xq, xkv, temp, wsb, wsb + 65536, wsb + 131072, wsb + 196608, out);
  } else {
    (void)hipFuncSetAttribute((const void*)&wsmdta_old<false>,
                              hipFuncAttributeMaxDynamicSharedMemorySize, SMEM_OLD);
    wsmdta_old<false><<<dim3(1152), dim3(512), SMEM_OLD, stream>>>(
        xq, xkv, temp, Wq, Wk, Wv, Wo, out);
  }
}